// Round 6
// baseline (270.462 us; speedup 1.0000x reference)
//
#include <hip/hip_runtime.h>
#include <hip/hip_bf16.h>

typedef __attribute__((ext_vector_type(8))) short s16x8;   // 8 bf16 (4 VGPRs)
typedef __attribute__((ext_vector_type(4))) float f32x4;
typedef unsigned short u16;
typedef unsigned int u32;

#define SDIM 2048
#define BDIM 2
#define HDIM 12
#define DDIM 64
#define EDIM 768
#define MDIM 4096          // S*B rows
#define SCALE_Q 0.125f     // D^-0.5
#define HFRAG 131072       // per-head fragment-tensor elements (2048*64)
#define NBODY 32           // 64-key bodies per wave (full 2048 keys)
#define NCHUNK 8           // 256-key chunks

static __device__ __forceinline__ f32x4 zero4() {
    f32x4 v; v[0] = v[1] = v[2] = v[3] = 0.f; return v;
}

// fp32 -> bf16 bits, round-to-nearest-even
static __device__ __forceinline__ u16 f2b(float x) {
    u32 u = __builtin_bit_cast(u32, x);
    u32 lsb = (u >> 16) & 1u;
    u += 0x7fffu + lsb;
    return (u16)(u >> 16);
}

static __device__ __forceinline__ f32x4 mfma16(s16x8 a, s16x8 b, f32x4 c) {
    return __builtin_amdgcn_mfma_f32_16x16x32_bf16(a, b, c, 0, 0, 0);
}

// async global -> LDS, 16B per lane. LDS dest = wave-uniform base + lane*16.
static __device__ __forceinline__ void gload_lds16(const void* g, void* l) {
    __builtin_amdgcn_global_load_lds(
        (const __attribute__((address_space(1))) void*)g,
        (__attribute__((address_space(3))) void*)l, 16, 0, 0);
}

// ---------------------------------------------------------------------------
// mask -> bitmask (128 u32; bit k = key k masked). Storage encoding of the
// bool array is unknown (bool bytes / int32 / float32): detect deterministically.
// ---------------------------------------------------------------------------
__global__ void mask_bits_kernel(const u32* __restrict__ raw, u32* __restrict__ outbits) {
    __shared__ int okInt, okFloat;
    int t = threadIdx.x;
    if (t == 0) { okInt = 1; okFloat = 1; }
    __syncthreads();
    int li = 1, lf = 1;
    for (int i = t; i < 1024; i += blockDim.x) {
        u32 v = raw[i];
        if (v > 1u) li = 0;
        if (v != 0u && v != 0x3F800000u) lf = 0;
    }
    if (!li) atomicAnd(&okInt, 0);
    if (!lf) atomicAnd(&okFloat, 0);
    __syncthreads();
    const unsigned char* rb = (const unsigned char*)raw;
    if (t < (BDIM * SDIM) / 32) {
        u32 bits = 0;
        for (int j = 0; j < 32; ++j) {
            int i = t * 32 + j;
            int v;
            if (okInt)        v = (int)raw[i];
            else if (okFloat) v = (raw[i] != 0u) ? 1 : 0;
            else              v = (int)rb[i];
            bits |= (v ? 1u : 0u) << j;
        }
        outbits[t] = bits;
    }
}

// ---------------------------------------------------------------------------
// fp32 -> bf16 bulk conversion (8 elems/thread)
// ---------------------------------------------------------------------------
__global__ __launch_bounds__(256) void conv_f32_bf16(
    const float* __restrict__ s, u16* __restrict__ d, int n8)
{
    int i = blockIdx.x * 256 + threadIdx.x;
    if (i >= n8) return;
    float4 x0 = ((const float4*)s)[(size_t)i * 2];
    float4 x1 = ((const float4*)s)[(size_t)i * 2 + 1];
    uint4 o;
    o.x = (u32)f2b(x0.x) | ((u32)f2b(x0.y) << 16);
    o.y = (u32)f2b(x0.z) | ((u32)f2b(x0.w) << 16);
    o.z = (u32)f2b(x1.x) | ((u32)f2b(x1.y) << 16);
    o.w = (u32)f2b(x1.z) | ((u32)f2b(x1.w) << 16);
    ((uint4*)d)[i] = o;
}

// ---------------------------------------------------------------------------
// C = (A @ W^T + bias) * scale.  A: MDIMxEDIM bf16, W: EDIMxEDIM bf16.
// mode=0: fp32 row-major (final output); mode=1: bf16 [bh][s][d] (Q);
// mode=3: K fragment-major; mode=4: V fragment-major.
// ---------------------------------------------------------------------------
__global__ __launch_bounds__(256) void gemm_xwT(
    const u16* __restrict__ A, const u16* __restrict__ Wb,
    const float* __restrict__ bias, float scale,
    u16* __restrict__ out_sc, float* __restrict__ out_rm, int mode)
{
    __shared__ u16 Al[64 * 56];
    __shared__ u16 Bl[64 * 56];
    int tid = threadIdx.x;
    int mb = blockIdx.x * 64, nb = blockIdx.y * 64;
    int lane = tid & 63, w = tid >> 6;
    int r16 = lane & 15, g4 = lane >> 4;
    int wm = w >> 1, wn = w & 1;

    f32x4 acc[2][2];
    acc[0][0] = zero4(); acc[0][1] = zero4(); acc[1][0] = zero4(); acc[1][1] = zero4();

    int srow = tid >> 2, scol = (tid & 3) * 8;

    for (int kb = 0; kb < EDIM; kb += 32) {
        __syncthreads();
        *(uint4*)&Al[srow * 56 + scol] =
            *(const uint4*)&A[(size_t)(mb + srow) * EDIM + kb + scol];
        *(uint4*)&Bl[srow * 56 + scol] =
            *(const uint4*)&Wb[(size_t)(nb + srow) * EDIM + kb + scol];
        __syncthreads();
        s16x8 a[2], bb[2];
        #pragma unroll
        for (int mi = 0; mi < 2; ++mi)
            a[mi] = *(const s16x8*)&Al[(wm * 32 + mi * 16 + r16) * 56 + g4 * 8];
        #pragma unroll
        for (int ni = 0; ni < 2; ++ni)
            bb[ni] = *(const s16x8*)&Bl[(wn * 32 + ni * 16 + r16) * 56 + g4 * 8];
        #pragma unroll
        for (int mi = 0; mi < 2; ++mi)
            #pragma unroll
            for (int ni = 0; ni < 2; ++ni)
                acc[mi][ni] = mfma16(a[mi], bb[ni], acc[mi][ni]);
    }

    #pragma unroll
    for (int mi = 0; mi < 2; ++mi) {
        #pragma unroll
        for (int ni = 0; ni < 2; ++ni) {
            int n = nb + wn * 32 + ni * 16 + r16;
            float bv = bias[n];
            #pragma unroll
            for (int r = 0; r < 4; ++r) {
                int m = mb + wm * 32 + mi * 16 + g4 * 4 + r;
                float c = (acc[mi][ni][r] + bv) * scale;
                if (mode == 1) {
                    int s_ = m >> 1, b_ = m & 1, h_ = n >> 6, d_ = n & 63;
                    out_sc[((size_t)(b_ * HDIM + h_) * SDIM + s_) * DDIM + d_] = f2b(c);
                } else if (mode == 3) {
                    int s_ = m >> 1, b_ = m & 1, h_ = n >> 6, d_ = n & 63;
                    size_t p = (size_t)(b_ * HDIM + h_) * HFRAG
                             + (size_t)(s_ >> 4) * 1024 + (size_t)((d_ >> 5) & 1) * 512
                             + (size_t)(((d_ >> 3) & 3) * 16 + (s_ & 15)) * 8 + (d_ & 7);
                    out_sc[p] = f2b(c);
                } else if (mode == 4) {
                    int s_ = m >> 1, b_ = m & 1, h_ = n >> 6, d_ = n & 63;
                    size_t p = (size_t)(b_ * HDIM + h_) * HFRAG
                             + (size_t)(s_ >> 5) * 2048 + (size_t)((d_ >> 4) & 3) * 512
                             + (size_t)(((s_ >> 3) & 3) * 16 + (d_ & 15)) * 8 + (s_ & 7);
                    out_sc[p] = f2b(c);
                } else {
                    out_rm[(size_t)m * EDIM + n] = c;
                }
            }
        }
    }
}

// ---------------------------------------------------------------------------
// Fused flash attention v6 — page-friendly bias bursts.
// Grid (S/16, B*H); block = 64 threads = 1 wave owning 16 q-rows x all 2048 keys.
// Bias consumed in 256-key chunks: LDS ring[2][16 rows][1KB]; each row staged by
// ONE gload_lds (64 lanes x 16B = 1KB contiguous burst). Next chunk's 16 DMAs
// are issued 4-per-body; counted waits vmcnt(20)/vmcnt(24) never drain the
// pipeline. Source-XOR (involution) within each row's 64 float4 units makes the
// bias ds_read_b128 <=2-way bank-conflict.
// 64-key bodies: swapped QK^T (k lane-local), one softmax chain per body,
// K/V register fragments depth-1 double-buffered (16 loads/body, fragment-major).
// ---------------------------------------------------------------------------
struct KV { s16x8 ka[4][2]; s16x8 va[2][4]; };

__global__ __launch_bounds__(64) void attn_fused(
    const u16* __restrict__ qw, const u16* __restrict__ kf_g,
    const u16* __restrict__ vf_g, const float* __restrict__ bias,
    const u32* __restrict__ maskBits, u16* __restrict__ attn_out)
{
    __shared__ float Ring[2][4096];    // 2 x 16 rows x 256 floats (16KB each)
    __shared__ u16 Pl[16 * 72];        // P transpose buffer (stride 72)

    int qt = blockIdx.x, bh = blockIdx.y;
    int lane = threadIdx.x;
    int r16 = lane & 15, g4 = lane >> 4;
    int qbase = qt * 16;
    int b_ = bh / HDIM, h_ = bh % HDIM;
    const u16* Q  = qw   + (size_t)bh * SDIM * DDIM;
    const u16* KF = kf_g + (size_t)bh * HFRAG;
    const u16* VF = vf_g + (size_t)bh * HFRAG;
    const float* BrowQ = bias + (size_t)bh * SDIM * SDIM + (size_t)qbase * SDIM;
    const u32* mB = maskBits + b_ * (SDIM / 32);

    s16x8 qf0 = *(const s16x8*)&Q[(size_t)(qbase + r16) * DDIM + g4 * 8];
    s16x8 qf1 = *(const s16x8*)&Q[(size_t)(qbase + r16) * DDIM + g4 * 8 + 32];

    f32x4 accO[4];
    #pragma unroll
    for (int dt = 0; dt < 4; ++dt) accO[dt] = zero4();
    float m_run = -1e30f, l_run = 0.f;       // for column q = r16

    // K/V register fragments for body t (64 keys): 8 K + 8 V contiguous loads
    auto issue_kv = [&](int t, KV& dst) {
        int tc = t < NBODY ? t : NBODY - 1;  // clamped (uniform vm count)
        const u16* KT = KF + (size_t)(tc * 4) * 1024;
        #pragma unroll
        for (int kt = 0; kt < 4; ++kt)
            #pragma unroll
            for (int c = 0; c < 2; ++c)
                dst.ka[kt][c] = *(const s16x8*)&KT[kt * 1024 + c * 512 + lane * 8];
        const u16* VT = VF + (size_t)(tc * 2) * 2048;
        #pragma unroll
        for (int ch = 0; ch < 2; ++ch)
            #pragma unroll
            for (int dt = 0; dt < 4; ++dt)
                dst.va[ch][dt] = *(const s16x8*)&VT[ch * 2048 + dt * 512 + lane * 8];
    };

    // stage rows (t&3)*4..+3 of chunk (t>>2)+1 into its ring slot; one 1KB
    // contiguous burst per row; source XOR-permuted within the row (involution)
    auto stage_slice = [&](int t) {
        int cn = (t >> 2) + 1;
        int cc = cn < NCHUNK ? cn : NCHUNK - 1;   // clamped (uniform vm count)
        float* slot = Ring[cn & 1];
        #pragma unroll
        for (int j = 0; j < 4; ++j) {
            int q = (t & 3) * 4 + j;
            gload_lds16(&BrowQ[(size_t)q * SDIM + cc * 256 + ((lane ^ (q & 7)) << 2)],
                        &slot[q * 256]);
        }
    };

    auto compute = [&](int t, KV& cur) {
        int b4 = t & 3;
        const float* Bs = Ring[(t >> 2) & 1];
        // QK^T swapped: sc[kt][r] = S[k = t*64 + 16kt + 4g4 + r][q = r16]
        f32x4 sc[4];
        #pragma unroll
        for (int kt = 0; kt < 4; ++kt)
            sc[kt] = mfma16(cur.ka[kt][1], qf1, mfma16(cur.ka[kt][0], qf0, zero4()));
        // bias (swizzled float4) + key-padding poison (scalar bitmask)
        u32 mw0 = mB[t * 2], mw1 = mB[t * 2 + 1];
        #pragma unroll
        for (int kt = 0; kt < 4; ++kt) {
            int u = (b4 * 16 + 4 * kt + g4) ^ (r16 & 7);
            float4 bc = *(const float4*)&Bs[r16 * 256 + u * 4];
            u32 mseg = ((kt & 2 ? mw1 : mw0) >> (16 * (kt & 1) + 4 * g4)) & 0xF;
            sc[kt][0] = (mseg & 1) ? -1e30f : sc[kt][0] + bc.x;
            sc[kt][1] = (mseg & 2) ? -1e30f : sc[kt][1] + bc.y;
            sc[kt][2] = (mseg & 4) ? -1e30f : sc[kt][2] + bc.z;
            sc[kt][3] = (mseg & 8) ? -1e30f : sc[kt][3] + bc.w;
        }
        // online softmax for column q = r16 (64 keys: 16 in-lane x 4 lane-groups)
        float pm = -1e30f;
        #pragma unroll
        for (int kt = 0; kt < 4; ++kt)
            pm = fmaxf(pm, fmaxf(fmaxf(sc[kt][0], sc[kt][1]), fmaxf(sc[kt][2], sc[kt][3])));
        pm = fmaxf(pm, __shfl_xor(pm, 16));
        pm = fmaxf(pm, __shfl_xor(pm, 32));
        float mn = fmaxf(m_run, pm);
        float alpha = __expf(m_run - mn);
        float p[16];
        #pragma unroll
        for (int kt = 0; kt < 4; ++kt)
            #pragma unroll
            for (int r = 0; r < 4; ++r)
                p[kt * 4 + r] = __expf(sc[kt][r] - mn);
        float ps = 0.f;
        #pragma unroll
        for (int i = 0; i < 16; ++i) ps += p[i];
        ps += __shfl_xor(ps, 16);
        ps += __shfl_xor(ps, 32);
        l_run = l_run * alpha + ps;
        m_run = mn;
        // P -> bf16, packed: Pl[q = r16][k = 16kt + 4g4 + 0..3]
        #pragma unroll
        for (int kt = 0; kt < 4; ++kt) {
            uint2 pv;
            pv.x = (u32)f2b(p[kt * 4 + 0]) | ((u32)f2b(p[kt * 4 + 1]) << 16);
            pv.y = (u32)f2b(p[kt * 4 + 2]) | ((u32)f2b(p[kt * 4 + 3]) << 16);
            *(uint2*)&Pl[r16 * 72 + kt * 16 + g4 * 4] = pv;
        }
        // alpha (held at lane r16=q) -> row-form q = 4g4+r
        float aR0 = __shfl(alpha, g4 * 4 + 0);
        float aR1 = __shfl(alpha, g4 * 4 + 1);
        float aR2 = __shfl(alpha, g4 * 4 + 2);
        float aR3 = __shfl(alpha, g4 * 4 + 3);
        #pragma unroll
        for (int dt = 0; dt < 4; ++dt) {
            accO[dt][0] *= aR0;
            accO[dt][1] *= aR1;
            accO[dt][2] *= aR2;
            accO[dt][3] *= aR3;
        }
        // PV over 64 keys: 2 k-chunks
        s16x8 pf0 = *(const s16x8*)&Pl[r16 * 72 + g4 * 8];
        s16x8 pf1 = *(const s16x8*)&Pl[r16 * 72 + 32 + g4 * 8];
        #pragma unroll
        for (int dt = 0; dt < 4; ++dt)
            accO[dt] = mfma16(pf1, cur.va[1][dt], mfma16(pf0, cur.va[0][dt], accO[dt]));
    };

    // prologue: kv(0) + all 16 rows of chunk 0
    KV A, B;
    issue_kv(0, A);
    #pragma unroll
    for (int q = 0; q < 16; ++q)
        gload_lds16(&BrowQ[(size_t)q * SDIM + ((lane ^ (q & 7)) << 2)], &Ring[0][q * 256]);

    for (int t4 = 0; t4 < NBODY; t4 += 4) {
        issue_kv(t4 + 1, B); stage_slice(t4);
        asm volatile("s_waitcnt vmcnt(20)" ::: "memory");
        __builtin_amdgcn_sched_barrier(0);
        compute(t4, A);

        issue_kv(t4 + 2, A); stage_slice(t4 + 1);
        asm volatile("s_waitcnt vmcnt(24)" ::: "memory");
        __builtin_amdgcn_sched_barrier(0);
        compute(t4 + 1, B);

        issue_kv(t4 + 3, B); stage_slice(t4 + 2);
        asm volatile("s_waitcnt vmcnt(24)" ::: "memory");
        __builtin_amdgcn_sched_barrier(0);
        compute(t4 + 2, A);

        issue_kv(t4 + 4, A); stage_slice(t4 + 3);
        asm volatile("s_waitcnt vmcnt(24)" ::: "memory");
        __builtin_amdgcn_sched_barrier(0);
        compute(t4 + 3, B);
    }

    // epilogue: redistribute l (column-form at lane q=r16) to row-form, write out
    float lR[4];
    #pragma unroll
    for (int r = 0; r < 4; ++r) lR[r] = __shfl(l_run, g4 * 4 + r);
    #pragma unroll
    for (int dt = 0; dt < 4; ++dt) {
        #pragma unroll
        for (int r = 0; r < 4; ++r) {
            int q = g4 * 4 + r;
            float o = accO[dt][r] / lR[r];
            attn_out[((size_t)(qbase + q) * BDIM + b_) * EDIM + h_ * DDIM + dt * 16 + r16] = f2b(o);
        }
    }
}

extern "C" void kernel_launch(void* const* d_in, const int* in_sizes, int n_in,
                              void* d_out, int out_size, void* d_ws, size_t ws_size,
                              hipStream_t stream) {
    const float* query     = (const float*)d_in[0];
    const float* attn_bias = (const float*)d_in[1];
    const u32*   mask_raw  = (const u32*)d_in[2];
    const float* Wq = (const float*)d_in[3];
    const float* bq = (const float*)d_in[4];
    const float* Wk = (const float*)d_in[5];
    const float* bk = (const float*)d_in[6];
    const float* Wv = (const float*)d_in[7];
    const float* bv = (const float*)d_in[8];
    const float* Wo = (const float*)d_in[9];
    const float* bo = (const float*)d_in[10];
    float* out = (float*)d_out;

    // workspace layout: maskBits(16KB) | qws | kws | vws | aws(=qbf) | 4x Wbf
    char* ws = (char*)d_ws;
    u32* maskB = (u32*)ws;
    const size_t HEADSZ = (size_t)BDIM * HDIM * SDIM * DDIM;  // 3,145,728 elems
    const size_t WSZ = (size_t)EDIM * EDIM;                   //   589,824 elems
    u16* qws = (u16*)(ws + 16384);
    u16* kws = qws + HEADSZ;
    u16* vws = kws + HEADSZ;
    u16* aws = vws + HEADSZ;      // attn out; doubles as bf16 query (qbf)
    u16* qbf = aws;
    u16* wWq = aws + HEADSZ;
    u16* wWk = wWq + WSZ;
    u16* wWv = wWk + WSZ;
    u16* wWo = wWv + WSZ;

    mask_bits_kernel<<<1, 256, 0, stream>>>(mask_raw, maskB);

    conv_f32_bf16<<<(int)(MDIM * EDIM / 8 / 256), 256, 0, stream>>>(query, qbf, MDIM * EDIM / 8);
    conv_f32_bf16<<<(int)(WSZ / 8 / 256), 256, 0, stream>>>(Wq, wWq, (int)(WSZ / 8));
    conv_f32_bf16<<<(int)(WSZ / 8 / 256), 256, 0, stream>>>(Wk, wWk, (int)(WSZ / 8));
    conv_f32_bf16<<<(int)(WSZ / 8 / 256), 256, 0, stream>>>(Wv, wWv, (int)(WSZ / 8));
    conv_f32_bf16<<<(int)(WSZ / 8 / 256), 256, 0, stream>>>(Wo, wWo, (int)(WSZ / 8));

    dim3 gg(MDIM / 64, EDIM / 64);
    gemm_xwT<<<gg, 256, 0, stream>>>(qbf, wWq, bq, SCALE_Q, qws, nullptr, 1);
    gemm_xwT<<<gg, 256, 0, stream>>>(qbf, wWk, bk, 1.0f,    kws, nullptr, 3);
    gemm_xwT<<<gg, 256, 0, stream>>>(qbf, wWv, bv, 1.0f,    vws, nullptr, 4);

    dim3 ga(SDIM / 16, BDIM * HDIM);
    attn_fused<<<ga, 64, 0, stream>>>(qws, kws, vws, attn_bias, maskB, aws);

    gemm_xwT<<<gg, 256, 0, stream>>>(aws, wWo, bo, 1.0f, nullptr, out, 0);
}

// Round 7
// 233.262 us; speedup vs baseline: 1.1595x; 1.1595x over previous
//
#include <hip/hip_runtime.h>
#include <hip/hip_bf16.h>

typedef __attribute__((ext_vector_type(8))) short s16x8;   // 8 bf16 (4 VGPRs)
typedef __attribute__((ext_vector_type(4))) float f32x4;
typedef unsigned short u16;
typedef unsigned int u32;

#define SDIM 2048
#define BDIM 2
#define HDIM 12
#define DDIM 64
#define EDIM 768
#define MDIM 4096          // S*B rows
#define SCALE_Q 0.125f     // D^-0.5
#define KSPLIT 1024        // keys per wave (2 waves split the 2048-key range)
#define NIT (KSPLIT / 32)  // 32 bodies per wave
#define HFRAG 131072       // per-head fragment-tensor elements (2048*64)

static __device__ __forceinline__ f32x4 zero4() {
    f32x4 v; v[0] = v[1] = v[2] = v[3] = 0.f; return v;
}

// fp32 -> bf16 bits, round-to-nearest-even
static __device__ __forceinline__ u16 f2b(float x) {
    u32 u = __builtin_bit_cast(u32, x);
    u32 lsb = (u >> 16) & 1u;
    u += 0x7fffu + lsb;
    return (u16)(u >> 16);
}

static __device__ __forceinline__ f32x4 mfma16(s16x8 a, s16x8 b, f32x4 c) {
    return __builtin_amdgcn_mfma_f32_16x16x32_bf16(a, b, c, 0, 0, 0);
}

// async global -> LDS, 16B per lane. LDS dest = wave-uniform base + lane*16.
static __device__ __forceinline__ void gload_lds16(const void* g, void* l) {
    __builtin_amdgcn_global_load_lds(
        (const __attribute__((address_space(1))) void*)g,
        (__attribute__((address_space(3))) void*)l, 16, 0, 0);
}

// ---------------------------------------------------------------------------
// mask -> bitmask (128 u32; bit k = key k masked). Storage encoding of the
// bool array is unknown (bool bytes / int32 / float32): detect deterministically.
// ---------------------------------------------------------------------------
__global__ void mask_bits_kernel(const u32* __restrict__ raw, u32* __restrict__ outbits) {
    __shared__ int okInt, okFloat;
    int t = threadIdx.x;
    if (t == 0) { okInt = 1; okFloat = 1; }
    __syncthreads();
    int li = 1, lf = 1;
    for (int i = t; i < 1024; i += blockDim.x) {
        u32 v = raw[i];
        if (v > 1u) li = 0;
        if (v != 0u && v != 0x3F800000u) lf = 0;
    }
    if (!li) atomicAnd(&okInt, 0);
    if (!lf) atomicAnd(&okFloat, 0);
    __syncthreads();
    const unsigned char* rb = (const unsigned char*)raw;
    if (t < (BDIM * SDIM) / 32) {
        u32 bits = 0;
        for (int j = 0; j < 32; ++j) {
            int i = t * 32 + j;
            int v;
            if (okInt)        v = (int)raw[i];
            else if (okFloat) v = (raw[i] != 0u) ? 1 : 0;
            else              v = (int)rb[i];
            bits |= (v ? 1u : 0u) << j;
        }
        outbits[t] = bits;
    }
}

// ---------------------------------------------------------------------------
// fp32 -> bf16 bulk conversion (8 elems/thread)
// ---------------------------------------------------------------------------
__global__ __launch_bounds__(256) void conv_f32_bf16(
    const float* __restrict__ s, u16* __restrict__ d, int n8)
{
    int i = blockIdx.x * 256 + threadIdx.x;
    if (i >= n8) return;
    float4 x0 = ((const float4*)s)[(size_t)i * 2];
    float4 x1 = ((const float4*)s)[(size_t)i * 2 + 1];
    uint4 o;
    o.x = (u32)f2b(x0.x) | ((u32)f2b(x0.y) << 16);
    o.y = (u32)f2b(x0.z) | ((u32)f2b(x0.w) << 16);
    o.z = (u32)f2b(x1.x) | ((u32)f2b(x1.y) << 16);
    o.w = (u32)f2b(x1.z) | ((u32)f2b(x1.w) << 16);
    ((uint4*)d)[i] = o;
}

// ---------------------------------------------------------------------------
// C = (A @ W^T + bias) * scale.  A: MDIMxEDIM bf16, W: EDIMxEDIM bf16.
// mode=0: fp32 row-major (final output); mode=1: bf16 [bh][s][d] (Q);
// mode=3: K fragment-major; mode=4: V fragment-major.
// ---------------------------------------------------------------------------
__global__ __launch_bounds__(256) void gemm_xwT(
    const u16* __restrict__ A, const u16* __restrict__ Wb,
    const float* __restrict__ bias, float scale,
    u16* __restrict__ out_sc, float* __restrict__ out_rm, int mode)
{
    __shared__ u16 Al[64 * 56];
    __shared__ u16 Bl[64 * 56];
    int tid = threadIdx.x;
    int mb = blockIdx.x * 64, nb = blockIdx.y * 64;
    int lane = tid & 63, w = tid >> 6;
    int r16 = lane & 15, g4 = lane >> 4;
    int wm = w >> 1, wn = w & 1;

    f32x4 acc[2][2];
    acc[0][0] = zero4(); acc[0][1] = zero4(); acc[1][0] = zero4(); acc[1][1] = zero4();

    int srow = tid >> 2, scol = (tid & 3) * 8;

    for (int kb = 0; kb < EDIM; kb += 32) {
        __syncthreads();
        *(uint4*)&Al[srow * 56 + scol] =
            *(const uint4*)&A[(size_t)(mb + srow) * EDIM + kb + scol];
        *(uint4*)&Bl[srow * 56 + scol] =
            *(const uint4*)&Wb[(size_t)(nb + srow) * EDIM + kb + scol];
        __syncthreads();
        s16x8 a[2], bb[2];
        #pragma unroll
        for (int mi = 0; mi < 2; ++mi)
            a[mi] = *(const s16x8*)&Al[(wm * 32 + mi * 16 + r16) * 56 + g4 * 8];
        #pragma unroll
        for (int ni = 0; ni < 2; ++ni)
            bb[ni] = *(const s16x8*)&Bl[(wn * 32 + ni * 16 + r16) * 56 + g4 * 8];
        #pragma unroll
        for (int mi = 0; mi < 2; ++mi)
            #pragma unroll
            for (int ni = 0; ni < 2; ++ni)
                acc[mi][ni] = mfma16(a[mi], bb[ni], acc[mi][ni]);
    }

    #pragma unroll
    for (int mi = 0; mi < 2; ++mi) {
        #pragma unroll
        for (int ni = 0; ni < 2; ++ni) {
            int n = nb + wn * 32 + ni * 16 + r16;
            float bv = bias[n];
            #pragma unroll
            for (int r = 0; r < 4; ++r) {
                int m = mb + wm * 32 + mi * 16 + g4 * 4 + r;
                float c = (acc[mi][ni][r] + bv) * scale;
                if (mode == 1) {
                    int s_ = m >> 1, b_ = m & 1, h_ = n >> 6, d_ = n & 63;
                    out_sc[((size_t)(b_ * HDIM + h_) * SDIM + s_) * DDIM + d_] = f2b(c);
                } else if (mode == 3) {
                    int s_ = m >> 1, b_ = m & 1, h_ = n >> 6, d_ = n & 63;
                    size_t p = (size_t)(b_ * HDIM + h_) * HFRAG
                             + (size_t)(s_ >> 4) * 1024 + (size_t)((d_ >> 5) & 1) * 512
                             + (size_t)(((d_ >> 3) & 3) * 16 + (s_ & 15)) * 8 + (d_ & 7);
                    out_sc[p] = f2b(c);
                } else if (mode == 4) {
                    int s_ = m >> 1, b_ = m & 1, h_ = n >> 6, d_ = n & 63;
                    size_t p = (size_t)(b_ * HDIM + h_) * HFRAG
                             + (size_t)(s_ >> 5) * 2048 + (size_t)((d_ >> 4) & 3) * 512
                             + (size_t)(((s_ >> 3) & 3) * 16 + (d_ & 15)) * 8 + (s_ & 7);
                    out_sc[p] = f2b(c);
                } else {
                    out_rm[(size_t)m * EDIM + n] = c;
                }
            }
        }
    }
}

// ---------------------------------------------------------------------------
// Fused flash attention v7 — QBLK=32 (halved K/V request rate per q-row),
// XCD-swizzled block mapping (3 heads per XCD -> K/V L2-resident),
// R5's DMA bias ring (2 slots x 4KB, counted vmcnt(12), never drains),
// defer-max rescale skip.
// Grid flat = 64 qtiles x 24 heads; block = 128 = 2 waves (split-K x2).
// ---------------------------------------------------------------------------
struct KV { s16x8 k0, k1, k2, k3, v0, v1, v2, v3; };

__global__ __launch_bounds__(128) void attn_fused(
    const u16* __restrict__ qw, const u16* __restrict__ kf_g,
    const u16* __restrict__ vf_g, const float* __restrict__ bias,
    const u32* __restrict__ maskBits, u16* __restrict__ attn_out)
{
    __shared__ __align__(1024) unsigned char SM[21504];
    // per wave: [0,8192) bias ring 2x4KB; [8192,10752) P buf [32][40] u16.
    // epilogue reuse: As[64][68] f32 (17408B) + Ml/Ll (512B).

    // XCD swizzle: flat%8 = XCD -> give each XCD a contiguous 192-block chunk
    // (= 3 heads x 64 qtiles) so its L2 holds 3 heads' K+V (1.5MB < 4MB).
    int flat = blockIdx.y * 64 + blockIdx.x;
    int virt = (flat & 7) * 192 + (flat >> 3);
    int qt = virt & 63, bh = virt >> 6;

    int tid = threadIdx.x;
    int w = tid >> 6, lane = tid & 63;
    int r16 = lane & 15, g4 = lane >> 4;
    int qbase = qt * 32;
    int b_ = bh / HDIM, h_ = bh % HDIM;
    const u16* Q  = qw   + (size_t)bh * SDIM * DDIM;
    const u16* KF = kf_g + (size_t)bh * HFRAG;
    const u16* VF = vf_g + (size_t)bh * HFRAG;
    const float* BrowQ = bias + (size_t)bh * SDIM * SDIM + (size_t)qbase * SDIM;
    const u32* mB = maskBits + b_ * (SDIM / 32);

    unsigned char* wb = SM + w * 10752;
    float* RingW = (float*)wb;            // 2 slots x 1024 floats ([32 q][32 k])
    u16*   Pl    = (u16*)(wb + 8192);     // [32 q][40 k-padded]

    // Q fragments for both 16-row halves
    s16x8 qf[2][2];
    #pragma unroll
    for (int h = 0; h < 2; ++h) {
        qf[h][0] = *(const s16x8*)&Q[(size_t)(qbase + 16 * h + r16) * DDIM + g4 * 8];
        qf[h][1] = *(const s16x8*)&Q[(size_t)(qbase + 16 * h + r16) * DDIM + g4 * 8 + 32];
    }

    f32x4 accO[2][4];
    #pragma unroll
    for (int h = 0; h < 2; ++h)
        #pragma unroll
        for (int dt = 0; dt < 4; ++dt) accO[h][dt] = zero4();
    float m_run[2] = {-1e30f, -1e30f}, l_run[2] = {0.f, 0.f};  // column q=r16 (+16h)

    const int k0 = w * KSPLIT;

    auto issue_kv = [&](int t, KV& dst) {
        int tc = t < NIT ? t : NIT - 1;              // clamped (uniform vm count)
        int kbn = k0 + tc * 32;
        const u16* KT = KF + (size_t)(kbn >> 4) * 1024;
        dst.k0 = *(const s16x8*)&KT[lane * 8];
        dst.k1 = *(const s16x8*)&KT[512 + lane * 8];
        dst.k2 = *(const s16x8*)&KT[1024 + lane * 8];
        dst.k3 = *(const s16x8*)&KT[1536 + lane * 8];
        const u16* VT = VF + (size_t)(kbn >> 5) * 2048;
        dst.v0 = *(const s16x8*)&VT[lane * 8];
        dst.v1 = *(const s16x8*)&VT[512 + lane * 8];
        dst.v2 = *(const s16x8*)&VT[1024 + lane * 8];
        dst.v3 = *(const s16x8*)&VT[1536 + lane * 8];
    };

    // stage bias tile t (32 rows x 128B) into ring slot t&1; 4 DMA of 1KB,
    // each covering 8 full rows; source XOR-permuted per row (involution).
    auto stage_bias = [&](int t) {
        int tc = t < NIT ? t : NIT - 1;              // clamped (uniform vm count)
        int kb = k0 + tc * 32;
        unsigned char* slot = (unsigned char*)(RingW + (t & 1) * 1024);
        int sq = (lane & 7) ^ ((lane >> 3) & 7);
        #pragma unroll
        for (int j = 0; j < 4; ++j) {
            int row = j * 8 + (lane >> 3);
            gload_lds16(&BrowQ[(size_t)row * SDIM + kb + sq * 4], slot + j * 1024);
        }
    };

    auto compute = [&](int t, KV& cur) {
        u32 mw = mB[__builtin_amdgcn_readfirstlane((k0 + t * 32) >> 5)];
        const float* Bs = RingW + (t & 1) * 1024;
        // QK^T swapped, both halves: sc[h][kt][r] = S[k=16kt+4g4+r][q=16h+r16]
        f32x4 sc[2][2];
        #pragma unroll
        for (int h = 0; h < 2; ++h) {
            sc[h][0] = mfma16(cur.k1, qf[h][1], mfma16(cur.k0, qf[h][0], zero4()));
            sc[h][1] = mfma16(cur.k3, qf[h][1], mfma16(cur.k2, qf[h][0], zero4()));
        }
        // bias + mask poison
        #pragma unroll
        for (int h = 0; h < 2; ++h) {
            int rr = 16 * h + r16;
            #pragma unroll
            for (int kt = 0; kt < 2; ++kt) {
                float4 bc = *(const float4*)&Bs[rr * 32 + (((4 * kt + g4) ^ (r16 & 7)) * 4)];
                u32 mseg = (mw >> (16 * kt + 4 * g4)) & 0xF;
                sc[h][kt][0] = (mseg & 1) ? -1e30f : sc[h][kt][0] + bc.x;
                sc[h][kt][1] = (mseg & 2) ? -1e30f : sc[h][kt][1] + bc.y;
                sc[h][kt][2] = (mseg & 4) ? -1e30f : sc[h][kt][2] + bc.z;
                sc[h][kt][3] = (mseg & 8) ? -1e30f : sc[h][kt][3] + bc.w;
            }
        }
        // online softmax per half (column q = 16h + r16)
        #pragma unroll
        for (int h = 0; h < 2; ++h) {
            float pm = fmaxf(
                fmaxf(fmaxf(sc[h][0][0], sc[h][0][1]), fmaxf(sc[h][0][2], sc[h][0][3])),
                fmaxf(fmaxf(sc[h][1][0], sc[h][1][1]), fmaxf(sc[h][1][2], sc[h][1][3])));
            pm = fmaxf(pm, __shfl_xor(pm, 16));
            pm = fmaxf(pm, __shfl_xor(pm, 32));
            bool norescale = __all(pm <= m_run[h] + 4.f);
            float mn = norescale ? m_run[h] : fmaxf(m_run[h], pm);
            float p[8];
            #pragma unroll
            for (int kt = 0; kt < 2; ++kt)
                #pragma unroll
                for (int r = 0; r < 4; ++r)
                    p[kt * 4 + r] = __expf(sc[h][kt][r] - mn);
            float ps = ((p[0] + p[1]) + (p[2] + p[3])) + ((p[4] + p[5]) + (p[6] + p[7]));
            ps += __shfl_xor(ps, 16);
            ps += __shfl_xor(ps, 32);
            if (norescale) {
                l_run[h] += ps;
            } else {
                float alpha = __expf(m_run[h] - mn);
                l_run[h] = l_run[h] * alpha + ps;
                m_run[h] = mn;
                float aR0 = __shfl(alpha, g4 * 4 + 0);
                float aR1 = __shfl(alpha, g4 * 4 + 1);
                float aR2 = __shfl(alpha, g4 * 4 + 2);
                float aR3 = __shfl(alpha, g4 * 4 + 3);
                #pragma unroll
                for (int dt = 0; dt < 4; ++dt) {
                    accO[h][dt][0] *= aR0;
                    accO[h][dt][1] *= aR1;
                    accO[h][dt][2] *= aR2;
                    accO[h][dt][3] *= aR3;
                }
            }
            // pack P rows 16h+r16
            int rr = 16 * h + r16;
            #pragma unroll
            for (int kt = 0; kt < 2; ++kt) {
                uint2 pv;
                pv.x = (u32)f2b(p[kt * 4 + 0]) | ((u32)f2b(p[kt * 4 + 1]) << 16);
                pv.y = (u32)f2b(p[kt * 4 + 2]) | ((u32)f2b(p[kt * 4 + 3]) << 16);
                *(uint2*)&Pl[rr * 40 + kt * 16 + g4 * 4] = pv;
            }
        }
        // PV both halves (V fragments shared)
        #pragma unroll
        for (int h = 0; h < 2; ++h) {
            s16x8 pf = *(const s16x8*)&Pl[(16 * h + r16) * 40 + g4 * 8];
            accO[h][0] = mfma16(pf, cur.v0, accO[h][0]);
            accO[h][1] = mfma16(pf, cur.v1, accO[h][1]);
            accO[h][2] = mfma16(pf, cur.v2, accO[h][2]);
            accO[h][3] = mfma16(pf, cur.v3, accO[h][3]);
        }
    };

    // prologue
    KV A, B;
    issue_kv(0, A);
    stage_bias(0);

    for (int t = 0; t < NIT; t += 2) {
        issue_kv(t + 1, B);
        stage_bias(t + 1);
        asm volatile("s_waitcnt vmcnt(12)" ::: "memory");
        __builtin_amdgcn_sched_barrier(0);
        compute(t, A);

        issue_kv(t + 2, A);
        stage_bias(t + 2);
        asm volatile("s_waitcnt vmcnt(12)" ::: "memory");
        __builtin_amdgcn_sched_barrier(0);
        compute(t + 1, B);
    }

    // ---- combine the two waves' partials (reuse LDS) ----
    __syncthreads();
    float* As = (float*)SM;                 // [64][68]
    float* Ml = (float*)(SM + 17408);       // [64]
    float* Ll = Ml + 64;
    #pragma unroll
    for (int h = 0; h < 2; ++h)
        #pragma unroll
        for (int dt = 0; dt < 4; ++dt)
            #pragma unroll
            for (int r = 0; r < 4; ++r)
                As[(size_t)(w * 32 + 16 * h + g4 * 4 + r) * 68 + dt * 16 + r16] = accO[h][dt][r];
    if (g4 == 0) {
        #pragma unroll
        for (int h = 0; h < 2; ++h) {
            Ml[w * 32 + 16 * h + r16] = m_run[h];
            Ll[w * 32 + 16 * h + r16] = l_run[h];
        }
    }
    __syncthreads();

    #pragma unroll
    for (int h = 0; h < 2; ++h) {
        #pragma unroll
        for (int dg = 0; dg < 2; ++dg) {
            int d = w * 32 + dg * 16 + r16;
            #pragma unroll
            for (int r = 0; r < 4; ++r) {
                int q = 16 * h + g4 * 4 + r;
                float m0 = Ml[q], m1 = Ml[32 + q];
                float mt = fmaxf(m0, m1);
                float e0 = __expf(m0 - mt), e1 = __expf(m1 - mt);
                float lt = Ll[q] * e0 + Ll[32 + q] * e1;
                float o = (As[(size_t)q * 68 + d] * e0 + As[(size_t)(32 + q) * 68 + d] * e1) / lt;
                attn_out[((size_t)(qbase + q) * BDIM + b_) * EDIM + h_ * DDIM + d] = f2b(o);
            }
        }
    }
}

extern "C" void kernel_launch(void* const* d_in, const int* in_sizes, int n_in,
                              void* d_out, int out_size, void* d_ws, size_t ws_size,
                              hipStream_t stream) {
    const float* query     = (const float*)d_in[0];
    const float* attn_bias = (const float*)d_in[1];
    const u32*   mask_raw  = (const u32*)d_in[2];
    const float* Wq = (const float*)d_in[3];
    const float* bq = (const float*)d_in[4];
    const float* Wk = (const float*)d_in[5];
    const float* bk = (const float*)d_in[6];
    const float* Wv = (const float*)d_in[7];
    const float* bv = (const float*)d_in[8];
    const float* Wo = (const float*)d_in[9];
    const float* bo = (const float*)d_in[10];
    float* out = (float*)d_out;

    // workspace layout: maskBits(16KB) | qws | kws | vws | aws(=qbf) | 4x Wbf
    char* ws = (char*)d_ws;
    u32* maskB = (u32*)ws;
    const size_t HEADSZ = (size_t)BDIM * HDIM * SDIM * DDIM;  // 3,145,728 elems
    const size_t WSZ = (size_t)EDIM * EDIM;                   //   589,824 elems
    u16* qws = (u16*)(ws + 16384);
    u16* kws = qws + HEADSZ;
    u16* vws = kws + HEADSZ;
    u16* aws = vws + HEADSZ;      // attn out; doubles as bf16 query (qbf)
    u16* qbf = aws;
    u16* wWq = aws + HEADSZ;
    u16* wWk = wWq + WSZ;
    u16* wWv = wWk + WSZ;
    u16* wWo = wWv + WSZ;

    mask_bits_kernel<<<1, 256, 0, stream>>>(mask_raw, maskB);

    conv_f32_bf16<<<(int)(MDIM * EDIM / 8 / 256), 256, 0, stream>>>(query, qbf, MDIM * EDIM / 8);
    conv_f32_bf16<<<(int)(WSZ / 8 / 256), 256, 0, stream>>>(Wq, wWq, (int)(WSZ / 8));
    conv_f32_bf16<<<(int)(WSZ / 8 / 256), 256, 0, stream>>>(Wk, wWk, (int)(WSZ / 8));
    conv_f32_bf16<<<(int)(WSZ / 8 / 256), 256, 0, stream>>>(Wv, wWv, (int)(WSZ / 8));
    conv_f32_bf16<<<(int)(WSZ / 8 / 256), 256, 0, stream>>>(Wo, wWo, (int)(WSZ / 8));

    dim3 gg(MDIM / 64, EDIM / 64);
    gemm_xwT<<<gg, 256, 0, stream>>>(qbf, wWq, bq, SCALE_Q, qws, nullptr, 1);
    gemm_xwT<<<gg, 256, 0, stream>>>(qbf, wWk, bk, 1.0f,    kws, nullptr, 3);
    gemm_xwT<<<gg, 256, 0, stream>>>(qbf, wWv, bv, 1.0f,    vws, nullptr, 4);

    dim3 ga(64, BDIM * HDIM);
    attn_fused<<<ga, 128, 0, stream>>>(qws, kws, vws, attn_bias, maskB, aws);

    gemm_xwT<<<gg, 256, 0, stream>>>(aws, wWo, bo, 1.0f, nullptr, out, 0);
}